// Round 9
// baseline (125.490 us; speedup 1.0000x reference)
//
#include <hip/hip_runtime.h>
#include <hip/hip_bf16.h>

// Problem constants (setup_inputs): B=2, N=16384, M=1024, IN=OUT=256
#define NPTS    32768
#define K_DIM   256
#define O_DIM   256
#define M_ATOMS 1024

typedef __attribute__((ext_vector_type(8))) short short8;
typedef __attribute__((ext_vector_type(4))) float f32x4;

// RNE split v = hi + lo (both bf16).
__device__ __forceinline__ void split1(float v, short* h, short* l) {
  unsigned short hu = __bfloat16_as_ushort(__float2bfloat16(v));
  *h = (short)hu;
  float r = v - __uint_as_float((unsigned)hu << 16);
  *l = (short)__bfloat16_as_ushort(__float2bfloat16(r));
}

__device__ __forceinline__ void cvt8(const f32x4 f0, const f32x4 f1,
                                     short8* h, short8* l) {
#pragma unroll
  for (int j = 0; j < 4; ++j) {
    short hh, ll;
    split1(f0[j], &hh, &ll);
    (*h)[j] = hh; (*l)[j] = ll;
    split1(f1[j], &hh, &ll);
    (*h)[j + 4] = hh; (*l)[j + 4] = ll;
  }
}

// async global->LDS, 16B/lane; LDS dest wave-uniform base (HW adds lane*16).
__device__ __forceinline__ void async16(void* l, const void* g) {
  __builtin_amdgcn_global_load_lds(
      (const __attribute__((address_space(1))) void*)g,
      (__attribute__((address_space(3))) void*)l, 16, 0, 0);
}

// K0: W -> bf16 hi/lo, fragment-major [kc8][ct16][lane64][e8].
// col = ct*16 + (lane&15), k = kc*32 + (lane>>4)*8 + e   (verified R1-R8)
__global__ __launch_bounds__(256) void wprep_kernel(const float* __restrict__ W,
                                                    unsigned short* __restrict__ whF,
                                                    unsigned short* __restrict__ wlF) {
  int t = blockIdx.x * 256 + threadIdx.x;   // 0..8191
  int lane = t & 63;
  int ct = (t >> 6) & 15;
  int kc = t >> 10;
  int col = ct * 16 + (lane & 15);
  int k0 = kc * 32 + (lane >> 4) * 8;
  const float* src = W + (size_t)col * K_DIM + k0;
  f32x4 f0 = *(const f32x4*)(src);
  f32x4 f1 = *(const f32x4*)(src + 4);
  short8 h, l;
  cvt8(f0, f1, &h, &l);
  *(short8*)(whF + (size_t)t * 8) = h;
  *(short8*)(wlF + (size_t)t * 8) = l;
}

// K1: omega per point (standalone, R2-proven structure).
// 512 blocks x 256 thr; block = 64 points, 4 waves x 256 atoms each.
__global__ __launch_bounds__(256) void omega_kernel(
    const float* __restrict__ qc, const float* __restrict__ atoms,
    const float* __restrict__ fw1, const float* __restrict__ fb1,
    const float* __restrict__ fw2, const float* __restrict__ fb2,
    float* __restrict__ omg) {
  __shared__ f32x4 at4[M_ATOMS];            // (x,y,z,|a|^2)
  __shared__ float red[4][64];
  const int base = blockIdx.x * 64;
  const int batch = base >> 14;
  const float* A = atoms + (size_t)batch * M_ATOMS * 3;
  for (int i = threadIdx.x; i < M_ATOMS; i += 256) {
    const float* ap = A + i * 3;
    float ax = ap[0], ay = ap[1], az = ap[2];
    at4[i] = (f32x4){ax, ay, az, ax * ax + ay * ay + az * az};
  }
  __syncthreads();
  const int lane = threadIdx.x & 63;
  const int w = threadIdx.x >> 6;
  const int pt = base + lane;
  const float qx = qc[(size_t)pt * 3 + 0];
  const float qy = qc[(size_t)pt * 3 + 1];
  const float qz = qc[(size_t)pt * 3 + 2];
  float m0 = 3.0e38f, m1 = 3.0e38f, m2 = 3.0e38f, m3 = 3.0e38f;
  const int i0 = w * 256;
  for (int i = i0; i < i0 + 256; i += 4) {
    f32x4 v0 = at4[i + 0], v1 = at4[i + 1], v2 = at4[i + 2], v3 = at4[i + 3];
    float d;
    d = v0[0] * qx; d = __fmaf_rn(v0[1], qy, d); d = __fmaf_rn(v0[2], qz, d);
    m0 = fminf(m0, __fmaf_rn(d, -2.0f, v0[3]));
    d = v1[0] * qx; d = __fmaf_rn(v1[1], qy, d); d = __fmaf_rn(v1[2], qz, d);
    m1 = fminf(m1, __fmaf_rn(d, -2.0f, v1[3]));
    d = v2[0] * qx; d = __fmaf_rn(v2[1], qy, d); d = __fmaf_rn(v2[2], qz, d);
    m2 = fminf(m2, __fmaf_rn(d, -2.0f, v2[3]));
    d = v3[0] * qx; d = __fmaf_rn(v3[1], qy, d); d = __fmaf_rn(v3[2], qz, d);
    m3 = fminf(m3, __fmaf_rn(d, -2.0f, v3[3]));
  }
  red[w][lane] = fminf(fminf(m0, m1), fminf(m2, m3));
  __syncthreads();
  if (w == 0) {
    float md = fminf(fminf(red[0][lane], red[1][lane]),
                     fminf(red[2][lane], red[3][lane]));
    md += qx * qx + qy * qy + qz * qz;      // |q-a|^2 = |q|^2 - 2 q.a + |a|^2
    float mind = sqrtf(fmaxf(md, 1.0e-4f)); // sqrt/max monotone
    float facc = fb2[0];
#pragma unroll
    for (int j = 0; j < 16; ++j) {
      float z = fw1[j * 3 + 0] * qx + fw1[j * 3 + 1] * qy + fw1[j * 3 + 2] * qz + fb1[j];
      facc += fw2[j] * (fmaxf(z, 0.0f) + __logf(1.0f + __expf(-fabsf(z)))); // softplus
    }
    float ls = fminf(fmaxf(facc, 0.0f), 5.0f); // fmaxf(NaN,0)=0 == nan_to_num(clip)
    omg[pt] = 30.0f * (1.0f + ls * __expf(-mind));
  }
}

// K2: x -> bf16 hi/lo, fragment-major [rt2048][kc8][lane64][e8].
// row = rt*16 + (lane&15), k = kc*32 + (lane>>4)*8 + e. Pure streaming.
__global__ __launch_bounds__(256) void xprep_kernel(const float* __restrict__ x,
                                                    unsigned short* __restrict__ xh,
                                                    unsigned short* __restrict__ xl) {
  int u = blockIdx.x * 256 + threadIdx.x;   // 0..1048575
  int lane = u & 63;
  int kc = (u >> 6) & 7;
  int rt = u >> 9;
  int row = rt * 16 + (lane & 15);
  int k0 = kc * 32 + (lane >> 4) * 8;
  const float* src = x + (size_t)row * K_DIM + k0;
  f32x4 f0 = *(const f32x4*)(src);
  f32x4 f1 = *(const f32x4*)(src + 4);
  short8 h, l;
  cvt8(f0, f1, &h, &l);
  *(short8*)(xh + (size_t)u * 8) = h;       // coalesced 16B/lane
  *(short8*)(xl + (size_t)u * 8) = l;
}

// K3: GEMM + sin. 512 blocks x 256 thr (4 waves), 4 blocks/CU.
// Block: 128 rows x 128 cols (rb = bid>>1, ch = bid&1). Wave: 32 rows x 128 cols.
// A: coalesced 16B frag loads from xh/xl (no conversion). B: global_load_lds
// double-buffer, one barrier per kc. 48 MFMA per wave-kc.
__global__ __launch_bounds__(256, 4) void gemm_sin_kernel(
    const unsigned short* __restrict__ xh, const unsigned short* __restrict__ xl,
    const unsigned short* __restrict__ whF, const unsigned short* __restrict__ wlF,
    const float* __restrict__ omg, const float* __restrict__ bias,
    float* __restrict__ out) {
  __shared__ short8 bsh[2][2][8][64];       // [buf][hi/lo][ct][lane], 32 KB
  const int lane = threadIdx.x & 63;
  const int w = threadIdx.x >> 6;
  const int lrow = lane & 15;
  const int lk = lane >> 4;
  const int rb = blockIdx.x >> 1;           // row-block: rows [rb*128, +128)
  const int ch = blockIdx.x & 1;            // col-half:  cols [ch*128, +128)

  // ---- stage B(kc=0) into buf 0: this half's 8KB hi + 8KB lo ----
  const char* whB = (const char*)whF + ch * 8192;
  const char* wlB = (const char*)wlF + ch * 8192;
  {
    char* dh = (char*)&bsh[0][0][0][0] + w * 2048;
    char* dl = (char*)&bsh[0][1][0][0] + w * 2048;
    const int so = w * 2048 + lane * 16;
    async16(dh, whB + so);
    async16(dh + 1024, whB + so + 1024);
    async16(dl, wlB + so);
    async16(dl + 1024, wlB + so + 1024);
  }

  // ---- A fragment pointers (frag-major; unit = short8) ----
  // element (rt, kc): (rt*8 + kc)*64 + lane ; wave owns rt0 = rb*8 + w*2, rt0+1
  const int rt0 = rb * 8 + w * 2;
  const short8* AH = (const short8*)xh + (size_t)rt0 * 512 + lane;
  const short8* AL = (const short8*)xl + (size_t)rt0 * 512 + lane;
  short8 ah0 = AH[0], ah1 = AH[512];
  short8 al0 = AL[0], al1 = AL[512];

  f32x4 acc[2][8];
#pragma unroll
  for (int t = 0; t < 2; ++t)
#pragma unroll
    for (int ct = 0; ct < 8; ++ct) acc[t][ct] = (f32x4){0.f, 0.f, 0.f, 0.f};

  __syncthreads();                          // B(0) staged (drains vmcnt)

#pragma unroll 1
  for (int kc = 0; kc < 8; ++kc) {
    const int cur = kc & 1;
    short8 nh0, nh1, nl0, nl1;
    if (kc < 7) {
      // stage B(kc+1) into the other buffer (async, no VGPR cost)
      char* dh = (char*)&bsh[cur ^ 1][0][0][0] + w * 2048;
      char* dl = (char*)&bsh[cur ^ 1][1][0][0] + w * 2048;
      const char* sh = whB + (kc + 1) * 16384 + w * 2048 + lane * 16;
      const char* sl = wlB + (kc + 1) * 16384 + w * 2048 + lane * 16;
      async16(dh, sh);
      async16(dh + 1024, sh + 1024);
      async16(dl, sl);
      async16(dl + 1024, sl + 1024);
      // prefetch A(kc+1): 4 coalesced 16B loads
      nh0 = AH[(kc + 1) * 64];
      nh1 = AH[512 + (kc + 1) * 64];
      nl0 = AL[(kc + 1) * 64];
      nl1 = AL[512 + (kc + 1) * 64];
    }
    // 16 ds_read_b128 + 48 MFMA
#pragma unroll
    for (int ct = 0; ct < 8; ++ct) {
      short8 bh = bsh[cur][0][ct][lane];
      short8 bl = bsh[cur][1][ct][lane];
      acc[0][ct] = __builtin_amdgcn_mfma_f32_16x16x32_bf16(ah0, bh, acc[0][ct], 0, 0, 0);
      acc[1][ct] = __builtin_amdgcn_mfma_f32_16x16x32_bf16(ah1, bh, acc[1][ct], 0, 0, 0);
      acc[0][ct] = __builtin_amdgcn_mfma_f32_16x16x32_bf16(al0, bh, acc[0][ct], 0, 0, 0);
      acc[1][ct] = __builtin_amdgcn_mfma_f32_16x16x32_bf16(al1, bh, acc[1][ct], 0, 0, 0);
      acc[0][ct] = __builtin_amdgcn_mfma_f32_16x16x32_bf16(ah0, bl, acc[0][ct], 0, 0, 0);
      acc[1][ct] = __builtin_amdgcn_mfma_f32_16x16x32_bf16(ah1, bl, acc[1][ct], 0, 0, 0);
    }
    if (kc < 7) {
      ah0 = nh0; ah1 = nh1; al0 = nl0; al1 = nl1;
    }
    __syncthreads();                        // stage(kc+1) done & buf reads done
  }

  // ---- epilogue: omega (global), bias, sin, store ----
  const int rowbase = rb * 128 + w * 32;
  float om[2][4];
#pragma unroll
  for (int t = 0; t < 2; ++t)
#pragma unroll
    for (int j = 0; j < 4; ++j)
      om[t][j] = omg[rowbase + t * 16 + lk * 4 + j];

#pragma unroll
  for (int ct = 0; ct < 8; ++ct) {
    float bv = bias[ch * 128 + ct * 16 + lrow];
#pragma unroll
    for (int t = 0; t < 2; ++t) {
#pragma unroll
      for (int j = 0; j < 4; ++j) {
        float pre = acc[t][ct][j] + bv;
        out[(size_t)(rowbase + t * 16 + lk * 4 + j) * O_DIM + ch * 128 + ct * 16 + lrow] =
            __sinf(om[t][j] * pre);
      }
    }
  }
}

extern "C" void kernel_launch(void* const* d_in, const int* in_sizes, int n_in,
                              void* d_out, int out_size, void* d_ws, size_t ws_size,
                              hipStream_t stream) {
  (void)in_sizes; (void)n_in; (void)out_size; (void)ws_size;
  const float* x     = (const float*)d_in[0];
  const float* qc    = (const float*)d_in[1];
  const float* atoms = (const float*)d_in[2];
  const float* W     = (const float*)d_in[3];
  const float* b     = (const float*)d_in[4];
  const float* fw1   = (const float*)d_in[5];
  const float* fb1   = (const float*)d_in[6];
  const float* fw2   = (const float*)d_in[7];
  const float* fb2   = (const float*)d_in[8];
  float* out = (float*)d_out;

  // ws: whF 128KB | wlF 128KB | omg 128KB | xh 16MB | xl 16MB
  char* p = (char*)d_ws;
  unsigned short* whF = (unsigned short*)p;          p += 131072;
  unsigned short* wlF = (unsigned short*)p;          p += 131072;
  float* omg          = (float*)p;                   p += 131072;
  unsigned short* xh  = (unsigned short*)p;          p += (size_t)NPTS * K_DIM * 2;
  unsigned short* xl  = (unsigned short*)p;

  wprep_kernel<<<32, 256, 0, stream>>>(W, whF, wlF);
  omega_kernel<<<512, 256, 0, stream>>>(qc, atoms, fw1, fb1, fw2, fb2, omg);
  xprep_kernel<<<4096, 256, 0, stream>>>(x, xh, xl);
  gemm_sin_kernel<<<512, 256, 0, stream>>>(xh, xl, whF, wlF, omg, b, out);
}